// Round 2
// baseline (611.872 us; speedup 1.0000x reference)
//
#include <hip/hip_runtime.h>
#include <hip/hip_cooperative_groups.h>

namespace cg = cooperative_groups;

// Problem constants: x is (B=64, C=256, H=56, W=56) fp32.
#define B_   64
#define C_   256
#define BC   (B_ * C_)      // 16384 planes
#define CS   64             // squeeze channels
#define HW   3136           // 56*56
#define HW4  784            // HW / 4 (float4 count per plane)
#define HW4F 768            // 12 * 64 full wave iterations
#define HW4T 16             // tail float4s (lanes 0..15)

typedef float floatx4 __attribute__((ext_vector_type(4)));  // native vec for nt-store

__device__ __forceinline__ float fmin4(float4 v) {
    return fminf(fminf(v.x, v.y), fminf(v.z, v.w));
}
__device__ __forceinline__ float fmax4(float4 v) {
    return fmaxf(fmaxf(v.x, v.y), fmaxf(v.z, v.w));
}

__device__ __forceinline__ float quant1(float o, float s, float z, float inv_s) {
    float q = rintf(__builtin_fmaf(o, inv_s, z));
    q = fminf(fmaxf(q, 0.0f), 255.0f);
    return (q - z) * s;
}

// ---------------------------------------------------------------------------
// Fused cooperative kernel: pool -> (fc1+fc2) -> quant, one dispatch.
// Grid-stride over planes so any co-resident grid size works.
// Math order is bit-identical to the proven 3-kernel version.
// ---------------------------------------------------------------------------
__global__ __launch_bounds__(256, 4) void k_fused(
    const float* __restrict__ x,
    const float* __restrict__ w1, const float* __restrict__ b1,
    const float* __restrict__ w2, const float* __restrict__ b2,
    const float* __restrict__ act_range,
    float* __restrict__ out,
    float* __restrict__ pooled, float* __restrict__ xmn, float* __restrict__ xmx,
    float* __restrict__ g, float* __restrict__ pmn, float* __restrict__ pmx)
{
    cg::grid_group grid = cg::this_grid();
    const int t = threadIdx.x;
    const int wave = t >> 6, lane = t & 63;
    const int gwave = blockIdx.x * 4 + wave;
    const int nwave = gridDim.x * 4;

    // ---- Phase 1: per-plane sum / min / max (wave-per-plane, barrier-free) ----
    for (int bc = gwave; bc < BC; bc += nwave) {
        const float4* xp = (const float4*)(x + (size_t)bc * HW);
        float sum = 0.0f;
        float mn = 3.402823466e38f;
        float mx = -3.402823466e38f;
        #pragma unroll
        for (int k = 0; k < 12; ++k) {               // 12*64 = 768 float4s
            float4 v = xp[lane + k * 64];
            sum += (v.x + v.y) + (v.z + v.w);
            mn = fminf(mn, fmin4(v));
            mx = fmaxf(mx, fmax4(v));
        }
        if (lane < HW4T) {                           // tail: 768..783
            float4 v = xp[HW4F + lane];
            sum += (v.x + v.y) + (v.z + v.w);
            mn = fminf(mn, fmin4(v));
            mx = fmaxf(mx, fmax4(v));
        }
        for (int off = 32; off > 0; off >>= 1) {
            sum += __shfl_down(sum, off, 64);
            mn = fminf(mn, __shfl_down(mn, off, 64));
            mx = fmaxf(mx, __shfl_down(mx, off, 64));
        }
        if (lane == 0) {
            pooled[bc] = sum / (float)HW;
            xmn[bc] = mn;
            xmx[bc] = mx;
        }
    }
    __threadfence();           // device-scope: make pooled/xmn/xmx visible across XCDs
    grid.sync();

    // ---- Phase 2: fc1 + fc2 + per-b min/max (first 64 blocks do the work) ----
    __shared__ __align__(16) float p[C_];
    __shared__ __align__(16) float part[4][CS];
    __shared__ __align__(16) float hs[CS];
    __shared__ float smn[4], smx[4];
    for (int b = blockIdx.x; b < B_; b += gridDim.x) {
        p[t] = pooled[b * C_ + t];
        __syncthreads();
        {
            const int s_ = t & 63, q = t >> 6;
            const float4* wr = (const float4*)(w1 + s_ * C_ + q * 64);
            const float4* pr = (const float4*)(p + q * 64);
            float acc = 0.0f;
            #pragma unroll
            for (int k = 0; k < 16; ++k) {
                float4 w = wr[k], pv = pr[k];
                acc += w.x * pv.x + w.y * pv.y + w.z * pv.z + w.w * pv.w;
            }
            part[q][s_] = acc;
        }
        __syncthreads();
        if (t < CS) {
            float a = (part[0][t] + part[1][t]) + (part[2][t] + part[3][t]) + b1[t];
            hs[t] = fmaxf(a, 0.0f);
        }
        __syncthreads();
        float acc = b2[t];
        const float4* wr = (const float4*)(w2 + t * CS);
        const float4* hr = (const float4*)hs;
        #pragma unroll
        for (int k = 0; k < 16; ++k) {
            float4 w = wr[k], hv = hr[k];
            acc += w.x * hv.x + w.y * hv.y + w.z * hv.z + w.w * hv.w;
        }
        float gg = fminf(fmaxf(acc / 6.0f + 0.5f, 0.0f), 1.0f);
        const int i = b * C_ + t;
        g[i] = gg;
        float mn = gg * xmn[i];
        float mx = gg * xmx[i];
        for (int off = 32; off > 0; off >>= 1) {
            mn = fminf(mn, __shfl_down(mn, off, 64));
            mx = fmaxf(mx, __shfl_down(mx, off, 64));
        }
        if (lane == 0) { smn[wave] = mn; smx[wave] = mx; }
        __syncthreads();
        if (t == 0) {
            pmn[b] = fminf(fminf(smn[0], smn[1]), fminf(smn[2], smn[3]));
            pmx[b] = fmaxf(fmaxf(smx[0], smx[1]), fmaxf(smx[2], smx[3]));
        }
        __syncthreads();       // protect LDS reuse if a block loops (grid < 64)
    }
    __threadfence();           // make g/pmn/pmx visible across XCDs
    grid.sync();

    // ---- Phase 3: recompute s/z per wave, then quant stream ----
    {
        float mn = pmn[lane];
        float mx = pmx[lane];
        for (int off = 32; off > 0; off >>= 1) {
            mn = fminf(mn, __shfl_xor(mn, off, 64));
            mx = fmaxf(mx, __shfl_xor(mx, off, 64));
        }
        const float new_min = act_range[0] * 0.999f + mn * 0.001f;
        const float new_max = act_range[1] * 0.999f + mx * 0.001f;
        const float s = (new_max - new_min) / 255.0f;
        const float z = -rintf(new_min / s);         // rintf = round-half-even = jnp.round
        const float inv_s = 1.0f / s;

        for (int bc = gwave; bc < BC; bc += nwave) {
            const float gv = g[bc];
            const float4* xp = (const float4*)(x + (size_t)bc * HW);
            floatx4* op = (floatx4*)(out + (size_t)bc * HW);
            #pragma unroll
            for (int k = 0; k < 12; ++k) {
                const int i = lane + k * 64;
                float4 v = xp[i];
                floatx4 r;
                r.x = quant1(v.x * gv, s, z, inv_s);
                r.y = quant1(v.y * gv, s, z, inv_s);
                r.z = quant1(v.z * gv, s, z, inv_s);
                r.w = quant1(v.w * gv, s, z, inv_s);
                __builtin_nontemporal_store(r, op + i);
            }
            if (lane < HW4T) {
                const int i = HW4F + lane;
                float4 v = xp[i];
                floatx4 r;
                r.x = quant1(v.x * gv, s, z, inv_s);
                r.y = quant1(v.y * gv, s, z, inv_s);
                r.z = quant1(v.z * gv, s, z, inv_s);
                r.w = quant1(v.w * gv, s, z, inv_s);
                __builtin_nontemporal_store(r, op + i);
            }
        }
    }
}

// ---------------------------------------------------------------------------
// Fallback path (proven 3-kernel version) in case cooperative launch fails.
// ---------------------------------------------------------------------------
__global__ __launch_bounds__(256) void k_pool(const float* __restrict__ x,
                                              float* __restrict__ pooled,
                                              float* __restrict__ xmn,
                                              float* __restrict__ xmx) {
    const int wave = threadIdx.x >> 6, lane = threadIdx.x & 63;
    const int bc = blockIdx.x * 4 + wave;
    const float4* xp = (const float4*)(x + (size_t)bc * HW);
    float sum = 0.0f;
    float mn = 3.402823466e38f, mx = -3.402823466e38f;
    #pragma unroll
    for (int k = 0; k < 12; ++k) {
        float4 v = xp[lane + k * 64];
        sum += (v.x + v.y) + (v.z + v.w);
        mn = fminf(mn, fmin4(v));
        mx = fmaxf(mx, fmax4(v));
    }
    if (lane < HW4T) {
        float4 v = xp[HW4F + lane];
        sum += (v.x + v.y) + (v.z + v.w);
        mn = fminf(mn, fmin4(v));
        mx = fmaxf(mx, fmax4(v));
    }
    for (int off = 32; off > 0; off >>= 1) {
        sum += __shfl_down(sum, off, 64);
        mn = fminf(mn, __shfl_down(mn, off, 64));
        mx = fmaxf(mx, __shfl_down(mx, off, 64));
    }
    if (lane == 0) {
        pooled[bc] = sum / (float)HW;
        xmn[bc] = mn;
        xmx[bc] = mx;
    }
}

__global__ __launch_bounds__(256) void k_mid(const float* __restrict__ pooled,
                                             const float* __restrict__ w1,
                                             const float* __restrict__ b1,
                                             const float* __restrict__ w2,
                                             const float* __restrict__ b2,
                                             const float* __restrict__ xmn,
                                             const float* __restrict__ xmx,
                                             float* __restrict__ g,
                                             float* __restrict__ pmn,
                                             float* __restrict__ pmx) {
    const int b = blockIdx.x;
    const int t = threadIdx.x;
    __shared__ __align__(16) float p[C_];
    __shared__ __align__(16) float part[4][CS];
    __shared__ __align__(16) float hs[CS];
    p[t] = pooled[b * C_ + t];
    __syncthreads();
    {
        const int s_ = t & 63, q = t >> 6;
        const float4* wr = (const float4*)(w1 + s_ * C_ + q * 64);
        const float4* pr = (const float4*)(p + q * 64);
        float acc = 0.0f;
        #pragma unroll
        for (int k = 0; k < 16; ++k) {
            float4 w = wr[k], pv = pr[k];
            acc += w.x * pv.x + w.y * pv.y + w.z * pv.z + w.w * pv.w;
        }
        part[q][s_] = acc;
    }
    __syncthreads();
    if (t < CS) {
        float a = (part[0][t] + part[1][t]) + (part[2][t] + part[3][t]) + b1[t];
        hs[t] = fmaxf(a, 0.0f);
    }
    __syncthreads();
    float acc = b2[t];
    const float4* wr = (const float4*)(w2 + t * CS);
    const float4* hr = (const float4*)hs;
    #pragma unroll
    for (int k = 0; k < 16; ++k) {
        float4 w = wr[k], hv = hr[k];
        acc += w.x * hv.x + w.y * hv.y + w.z * hv.z + w.w * hv.w;
    }
    float gg = fminf(fmaxf(acc / 6.0f + 0.5f, 0.0f), 1.0f);
    const int i = b * C_ + t;
    g[i] = gg;
    float mn = gg * xmn[i];
    float mx = gg * xmx[i];
    for (int off = 32; off > 0; off >>= 1) {
        mn = fminf(mn, __shfl_down(mn, off, 64));
        mx = fmaxf(mx, __shfl_down(mx, off, 64));
    }
    __shared__ float smn[4], smx[4];
    const int wave = t >> 6, lane = t & 63;
    if (lane == 0) { smn[wave] = mn; smx[wave] = mx; }
    __syncthreads();
    if (t == 0) {
        pmn[b] = fminf(fminf(smn[0], smn[1]), fminf(smn[2], smn[3]));
        pmx[b] = fmaxf(fmaxf(smx[0], smx[1]), fmaxf(smx[2], smx[3]));
    }
}

__global__ __launch_bounds__(256) void k_quant(const float* __restrict__ x,
                                               const float* __restrict__ g,
                                               const float* __restrict__ pmn,
                                               const float* __restrict__ pmx,
                                               const float* __restrict__ act_range,
                                               float* __restrict__ out) {
    const int wave = threadIdx.x >> 6, lane = threadIdx.x & 63;
    float mn = pmn[lane];
    float mx = pmx[lane];
    for (int off = 32; off > 0; off >>= 1) {
        mn = fminf(mn, __shfl_xor(mn, off, 64));
        mx = fmaxf(mx, __shfl_xor(mx, off, 64));
    }
    const float new_min = act_range[0] * 0.999f + mn * 0.001f;
    const float new_max = act_range[1] * 0.999f + mx * 0.001f;
    const float s = (new_max - new_min) / 255.0f;
    const float z = -rintf(new_min / s);
    const float inv_s = 1.0f / s;

    const int bc = blockIdx.x * 4 + wave;
    const float gv = g[bc];
    const float4* xp = (const float4*)(x + (size_t)bc * HW);
    floatx4* op = (floatx4*)(out + (size_t)bc * HW);
    #pragma unroll
    for (int k = 0; k < 12; ++k) {
        const int i = lane + k * 64;
        float4 v = xp[i];
        floatx4 r;
        r.x = quant1(v.x * gv, s, z, inv_s);
        r.y = quant1(v.y * gv, s, z, inv_s);
        r.z = quant1(v.z * gv, s, z, inv_s);
        r.w = quant1(v.w * gv, s, z, inv_s);
        __builtin_nontemporal_store(r, op + i);
    }
    if (lane < HW4T) {
        const int i = HW4F + lane;
        float4 v = xp[i];
        floatx4 r;
        r.x = quant1(v.x * gv, s, z, inv_s);
        r.y = quant1(v.y * gv, s, z, inv_s);
        r.z = quant1(v.z * gv, s, z, inv_s);
        r.w = quant1(v.w * gv, s, z, inv_s);
        __builtin_nontemporal_store(r, op + i);
    }
}

extern "C" void kernel_launch(void* const* d_in, const int* in_sizes, int n_in,
                              void* d_out, int out_size, void* d_ws, size_t ws_size,
                              hipStream_t stream) {
    const float* x         = (const float*)d_in[0];
    const float* w1        = (const float*)d_in[1];
    const float* b1        = (const float*)d_in[2];
    const float* w2        = (const float*)d_in[3];
    const float* b2        = (const float*)d_in[4];
    const float* act_range = (const float*)d_in[5];
    float* out = (float*)d_out;

    // ws floats: pooled[16384] | xmn[16384] | xmx[16384] | g[16384] | pmn[64] | pmx[64]
    float* ws     = (float*)d_ws;
    float* pooled = ws;
    float* xmn    = ws + BC;
    float* xmx    = ws + 2 * BC;
    float* g      = ws + 3 * BC;
    float* pmn    = ws + 4 * BC;
    float* pmx    = pmn + B_;

    // Co-residency-safe grid size (cached once; host-side query only).
    static int nblk = 0;
    if (nblk == 0) {
        int perCU = 0;
        hipError_t e = hipOccupancyMaxActiveBlocksPerMultiprocessor(&perCU, k_fused, 256, 0);
        if (e != hipSuccess || perCU < 1) perCU = 4;
        nblk = perCU * 256;          // 256 CUs
        if (nblk > 2048) nblk = 2048;
    }

    void* args[] = {(void*)&x, (void*)&w1, (void*)&b1, (void*)&w2, (void*)&b2,
                    (void*)&act_range, (void*)&out,
                    (void*)&pooled, (void*)&xmn, (void*)&xmx,
                    (void*)&g, (void*)&pmn, (void*)&pmx};
    hipError_t err = hipLaunchCooperativeKernel((void*)k_fused, dim3(nblk), dim3(256),
                                                args, 0, stream);
    if (err != hipSuccess) {
        // Proven 3-kernel fallback.
        k_pool <<<BC / 4, 256, 0, stream>>>(x, pooled, xmn, xmx);
        k_mid  <<<B_,     256, 0, stream>>>(pooled, w1, b1, w2, b2, xmn, xmx, g, pmn, pmx);
        k_quant<<<BC / 4, 256, 0, stream>>>(x, g, pmn, pmx, act_range, out);
    }
}

// Round 3
// 393.498 us; speedup vs baseline: 1.5550x; 1.5550x over previous
//
#include <hip/hip_runtime.h>

// Problem constants: x is (B=64, C=256, H=56, W=56) fp32.
#define B_   64
#define C_   256
#define BC   (B_ * C_)      // 16384 planes
#define CS   64             // squeeze channels
#define HW   3136           // 56*56
#define HW4  784            // HW / 4 (float4 count per plane)
#define HW4F 768            // 12 * 64 full wave iterations
#define HW4T 16             // tail float4s (lanes 0..15)

__device__ __forceinline__ float fmin4(float4 v) {
    return fminf(fminf(v.x, v.y), fminf(v.z, v.w));
}
__device__ __forceinline__ float fmax4(float4 v) {
    return fmaxf(fmaxf(v.x, v.y), fmaxf(v.z, v.w));
}

// Kernel 1: per-plane sum / min / max. Wave-per-plane, 4 planes per block.
// Barrier-free: each wave streams its 12.5 KB plane with 12 independent
// float4 loads per lane, then a pure-shfl reduction. No LDS, no __syncthreads.
// Plain loads on purpose: x must stay L3-resident for k_quant's second pass
// (R2 counters proved the second pass is fully L3-absorbed: FETCH = 1x x).
__global__ __launch_bounds__(256) void k_pool(const float* __restrict__ x,
                                              float* __restrict__ pooled,
                                              float* __restrict__ xmn,
                                              float* __restrict__ xmx) {
    const int wave = threadIdx.x >> 6, lane = threadIdx.x & 63;
    const int bc = blockIdx.x * 4 + wave;
    const float4* xp = (const float4*)(x + (size_t)bc * HW);

    float sum = 0.0f;
    float mn = 3.402823466e38f;
    float mx = -3.402823466e38f;
    #pragma unroll
    for (int k = 0; k < 12; ++k) {               // 12*64 = 768 float4s
        float4 v = xp[lane + k * 64];
        sum += (v.x + v.y) + (v.z + v.w);
        mn = fminf(mn, fmin4(v));
        mx = fmaxf(mx, fmax4(v));
    }
    if (lane < HW4T) {                           // tail: 768..783
        float4 v = xp[HW4F + lane];
        sum += (v.x + v.y) + (v.z + v.w);
        mn = fminf(mn, fmin4(v));
        mx = fmaxf(mx, fmax4(v));
    }
    for (int off = 32; off > 0; off >>= 1) {
        sum += __shfl_down(sum, off, 64);
        mn = fminf(mn, __shfl_down(mn, off, 64));
        mx = fmaxf(mx, __shfl_down(mx, off, 64));
    }
    if (lane == 0) {
        pooled[bc] = sum / (float)HW;
        xmn[bc] = mn;
        xmx[bc] = mx;
    }
}

// Kernel 2: fused fc1 + fc2 + per-b min/max. One block per batch b (64 blocks).
// h lives in LDS only (never written to global).
__global__ __launch_bounds__(256) void k_mid(const float* __restrict__ pooled,
                                             const float* __restrict__ w1,
                                             const float* __restrict__ b1,
                                             const float* __restrict__ w2,
                                             const float* __restrict__ b2,
                                             const float* __restrict__ xmn,
                                             const float* __restrict__ xmx,
                                             float* __restrict__ g,
                                             float* __restrict__ pmn,
                                             float* __restrict__ pmx) {
    const int b = blockIdx.x;
    const int t = threadIdx.x;
    __shared__ __align__(16) float p[C_];
    __shared__ __align__(16) float part[4][CS];
    __shared__ __align__(16) float hs[CS];
    p[t] = pooled[b * C_ + t];
    __syncthreads();

    // fc1: 256 threads = 64 outputs x 4 partial dots over the 256-wide input.
    {
        const int s_ = t & 63, q = t >> 6;
        const float4* wr = (const float4*)(w1 + s_ * C_ + q * 64);
        const float4* pr = (const float4*)(p + q * 64);
        float acc = 0.0f;
        #pragma unroll
        for (int k = 0; k < 16; ++k) {
            float4 w = wr[k], pv = pr[k];
            acc += w.x * pv.x + w.y * pv.y + w.z * pv.z + w.w * pv.w;
        }
        part[q][s_] = acc;
    }
    __syncthreads();
    if (t < CS) {
        float a = (part[0][t] + part[1][t]) + (part[2][t] + part[3][t]) + b1[t];
        hs[t] = fmaxf(a, 0.0f);
    }
    __syncthreads();

    // fc2 + hardsigmoid; fold per-(b,c) min/max of out via g*xmn / g*xmx (g>=0).
    float acc = b2[t];
    const float4* wr = (const float4*)(w2 + t * CS);
    const float4* hr = (const float4*)hs;
    #pragma unroll
    for (int k = 0; k < 16; ++k) {
        float4 w = wr[k], hv = hr[k];
        acc += w.x * hv.x + w.y * hv.y + w.z * hv.z + w.w * hv.w;
    }
    float gg = fminf(fmaxf(acc / 6.0f + 0.5f, 0.0f), 1.0f);
    const int i = b * C_ + t;
    g[i] = gg;
    float mn = gg * xmn[i];
    float mx = gg * xmx[i];
    for (int off = 32; off > 0; off >>= 1) {
        mn = fminf(mn, __shfl_down(mn, off, 64));
        mx = fmaxf(mx, __shfl_down(mx, off, 64));
    }
    __shared__ float smn[4], smx[4];
    const int wave = t >> 6, lane = t & 63;
    if (lane == 0) { smn[wave] = mn; smx[wave] = mx; }
    __syncthreads();
    if (t == 0) {
        pmn[b] = fminf(fminf(smn[0], smn[1]), fminf(smn[2], smn[3]));
        pmx[b] = fmaxf(fmaxf(smx[0], smx[1]), fmaxf(smx[2], smx[3]));
    }
}

__device__ __forceinline__ float quant1(float o, float s, float z, float inv_s) {
    float q = rintf(__builtin_fmaf(o, inv_s, z));
    q = fminf(fmaxf(q, 0.0f), 255.0f);
    return (q - z) * s;
}

// Kernel 3: out = fakequant(x * g[b,c]). Wave-per-plane, 4 planes per block.
// s/z/1/s recomputed redundantly per wave from pmn/pmx (bit-identical across
// waves: fmin/fmax chains are exact). x reads hit L3 (proven in R2: FETCH for
// both passes = 1x x size).
// CHANGE vs R1: PLAIN streaming stores instead of nontemporal. Theory: nt
// bypasses L2 write-combining; harness fills prove plain streaming writes
// sustain 6.7 TB/s on this part, so let out aggregate in L2 and stream out.
__global__ __launch_bounds__(256) void k_quant(const float* __restrict__ x,
                                               const float* __restrict__ g,
                                               const float* __restrict__ pmn,
                                               const float* __restrict__ pmx,
                                               const float* __restrict__ act_range,
                                               float* __restrict__ out) {
    const int wave = threadIdx.x >> 6, lane = threadIdx.x & 63;

    // inline sz: reduce 64 per-batch min/max, EMA, quant params
    float mn = pmn[lane];
    float mx = pmx[lane];
    for (int off = 32; off > 0; off >>= 1) {
        mn = fminf(mn, __shfl_xor(mn, off, 64));
        mx = fmaxf(mx, __shfl_xor(mx, off, 64));
    }
    const float new_min = act_range[0] * 0.999f + mn * 0.001f;
    const float new_max = act_range[1] * 0.999f + mx * 0.001f;
    const float s = (new_max - new_min) / 255.0f;
    const float z = -rintf(new_min / s);         // rintf = round-half-even = jnp.round
    const float inv_s = 1.0f / s;

    const int bc = blockIdx.x * 4 + wave;
    const float gv = g[bc];
    const float4* xp = (const float4*)(x + (size_t)bc * HW);
    float4* op = (float4*)(out + (size_t)bc * HW);

    #pragma unroll
    for (int k = 0; k < 12; ++k) {
        const int i = lane + k * 64;
        float4 v = xp[i];
        float4 r;
        r.x = quant1(v.x * gv, s, z, inv_s);
        r.y = quant1(v.y * gv, s, z, inv_s);
        r.z = quant1(v.z * gv, s, z, inv_s);
        r.w = quant1(v.w * gv, s, z, inv_s);
        op[i] = r;
    }
    if (lane < HW4T) {
        const int i = HW4F + lane;
        float4 v = xp[i];
        float4 r;
        r.x = quant1(v.x * gv, s, z, inv_s);
        r.y = quant1(v.y * gv, s, z, inv_s);
        r.z = quant1(v.z * gv, s, z, inv_s);
        r.w = quant1(v.w * gv, s, z, inv_s);
        op[i] = r;
    }
}

extern "C" void kernel_launch(void* const* d_in, const int* in_sizes, int n_in,
                              void* d_out, int out_size, void* d_ws, size_t ws_size,
                              hipStream_t stream) {
    const float* x         = (const float*)d_in[0];
    const float* w1        = (const float*)d_in[1];
    const float* b1        = (const float*)d_in[2];
    const float* w2        = (const float*)d_in[3];
    const float* b2        = (const float*)d_in[4];
    const float* act_range = (const float*)d_in[5];
    float* out = (float*)d_out;

    // ws floats: pooled[16384] | xmn[16384] | xmx[16384] | g[16384] | pmn[64] | pmx[64]
    float* ws     = (float*)d_ws;
    float* pooled = ws;
    float* xmn    = ws + BC;
    float* xmx    = ws + 2 * BC;
    float* g      = ws + 3 * BC;
    float* pmn    = ws + 4 * BC;
    float* pmx    = pmn + B_;

    k_pool <<<BC / 4, 256, 0, stream>>>(x, pooled, xmn, xmx);
    k_mid  <<<B_,     256, 0, stream>>>(pooled, w1, b1, w2, b2, xmn, xmx, g, pmn, pmx);
    k_quant<<<BC / 4, 256, 0, stream>>>(x, g, pmn, pmx, act_range, out);
}

// Round 5
// 384.302 us; speedup vs baseline: 1.5922x; 1.0239x over previous
//
#include <hip/hip_runtime.h>

// Problem constants: x is (B=64, C=256, H=56, W=56) fp32.
#define B_   64
#define C_   256
#define BC   (B_ * C_)      // 16384 planes
#define CS   64             // squeeze channels
#define HW   3136           // 56*56
#define HW4  784            // HW / 4 (float4 count per plane)
#define HW4F 768            // 12 * 64 full wave iterations
#define HW4T 16             // tail float4s (lanes 0..15)

typedef float floatx4 __attribute__((ext_vector_type(4)));  // native vec for nt-store

__device__ __forceinline__ float fmin4(float4 v) {
    return fminf(fminf(v.x, v.y), fminf(v.z, v.w));
}
__device__ __forceinline__ float fmax4(float4 v) {
    return fmaxf(fmaxf(v.x, v.y), fmaxf(v.z, v.w));
}

// Kernel 1: per-plane sum / min / max. Wave-per-plane, 4 planes per block.
// Barrier-free: each wave streams its 12.5 KB plane with 12 independent
// float4 loads per lane, then a pure-shfl reduction. No LDS, no __syncthreads.
__global__ __launch_bounds__(256) void k_pool(const float* __restrict__ x,
                                              float* __restrict__ pooled,
                                              float* __restrict__ xmn,
                                              float* __restrict__ xmx) {
    const int wave = threadIdx.x >> 6, lane = threadIdx.x & 63;
    const int bc = blockIdx.x * 4 + wave;
    const float4* xp = (const float4*)(x + (size_t)bc * HW);

    float sum = 0.0f;
    float mn = 3.402823466e38f;
    float mx = -3.402823466e38f;
    #pragma unroll
    for (int k = 0; k < 12; ++k) {               // 12*64 = 768 float4s
        float4 v = xp[lane + k * 64];
        sum += (v.x + v.y) + (v.z + v.w);
        mn = fminf(mn, fmin4(v));
        mx = fmaxf(mx, fmax4(v));
    }
    if (lane < HW4T) {                           // tail: 768..783
        float4 v = xp[HW4F + lane];
        sum += (v.x + v.y) + (v.z + v.w);
        mn = fminf(mn, fmin4(v));
        mx = fmaxf(mx, fmax4(v));
    }
    for (int off = 32; off > 0; off >>= 1) {
        sum += __shfl_down(sum, off, 64);
        mn = fminf(mn, __shfl_down(mn, off, 64));
        mx = fmaxf(mx, __shfl_down(mx, off, 64));
    }
    if (lane == 0) {
        pooled[bc] = sum / (float)HW;
        xmn[bc] = mn;
        xmx[bc] = mx;
    }
}

// Kernel 2: fused fc1 + fc2 + per-b min/max. One block per batch b (64 blocks).
// h lives in LDS only (never written to global).
__global__ __launch_bounds__(256) void k_mid(const float* __restrict__ pooled,
                                             const float* __restrict__ w1,
                                             const float* __restrict__ b1,
                                             const float* __restrict__ w2,
                                             const float* __restrict__ b2,
                                             const float* __restrict__ xmn,
                                             const float* __restrict__ xmx,
                                             float* __restrict__ g,
                                             float* __restrict__ pmn,
                                             float* __restrict__ pmx) {
    const int b = blockIdx.x;
    const int t = threadIdx.x;
    __shared__ __align__(16) float p[C_];
    __shared__ __align__(16) float part[4][CS];
    __shared__ __align__(16) float hs[CS];
    p[t] = pooled[b * C_ + t];
    __syncthreads();

    // fc1: 256 threads = 64 outputs x 4 partial dots over the 256-wide input.
    {
        const int s_ = t & 63, q = t >> 6;
        const float4* wr = (const float4*)(w1 + s_ * C_ + q * 64);
        const float4* pr = (const float4*)(p + q * 64);
        float acc = 0.0f;
        #pragma unroll
        for (int k = 0; k < 16; ++k) {
            float4 w = wr[k], pv = pr[k];
            acc += w.x * pv.x + w.y * pv.y + w.z * pv.z + w.w * pv.w;
        }
        part[q][s_] = acc;
    }
    __syncthreads();
    if (t < CS) {
        float a = (part[0][t] + part[1][t]) + (part[2][t] + part[3][t]) + b1[t];
        hs[t] = fmaxf(a, 0.0f);
    }
    __syncthreads();

    // fc2 + hardsigmoid; fold per-(b,c) min/max of out via g*xmn / g*xmx (g>=0).
    float acc = b2[t];
    const float4* wr = (const float4*)(w2 + t * CS);
    const float4* hr = (const float4*)hs;
    #pragma unroll
    for (int k = 0; k < 16; ++k) {
        float4 w = wr[k], hv = hr[k];
        acc += w.x * hv.x + w.y * hv.y + w.z * hv.z + w.w * hv.w;
    }
    float gg = fminf(fmaxf(acc / 6.0f + 0.5f, 0.0f), 1.0f);
    const int i = b * C_ + t;
    g[i] = gg;
    float mn = gg * xmn[i];
    float mx = gg * xmx[i];
    for (int off = 32; off > 0; off >>= 1) {
        mn = fminf(mn, __shfl_down(mn, off, 64));
        mx = fmaxf(mx, __shfl_down(mx, off, 64));
    }
    __shared__ float smn[4], smx[4];
    const int wave = t >> 6, lane = t & 63;
    if (lane == 0) { smn[wave] = mn; smx[wave] = mx; }
    __syncthreads();
    if (t == 0) {
        pmn[b] = fminf(fminf(smn[0], smn[1]), fminf(smn[2], smn[3]));
        pmx[b] = fmaxf(fmaxf(smx[0], smx[1]), fmaxf(smx[2], smx[3]));
    }
}

__device__ __forceinline__ float quant1(float o, float s, float z, float inv_s) {
    float q = rintf(__builtin_fmaf(o, inv_s, z));
    q = fminf(fmaxf(q, 0.0f), 255.0f);
    return (q - z) * s;
}

// Kernel 3: out = fakequant(x * g[b,c]). Wave-per-plane, 4 planes per block.
// s/z/1/s recomputed redundantly per wave from pmn/pmx (bit-identical across
// waves: fmin/fmax chains are exact). x reads hit L3 (R2 counters: FETCH for
// the whole fused op = 1x x size, so the second pass is L3-absorbed).
// Non-temporal stores: measured 9 us better than plain stores (R1 vs R3).
__global__ __launch_bounds__(256) void k_quant(const float* __restrict__ x,
                                               const float* __restrict__ g,
                                               const float* __restrict__ pmn,
                                               const float* __restrict__ pmx,
                                               const float* __restrict__ act_range,
                                               float* __restrict__ out) {
    const int wave = threadIdx.x >> 6, lane = threadIdx.x & 63;

    // inline sz: reduce 64 per-batch min/max, EMA, quant params
    float mn = pmn[lane];
    float mx = pmx[lane];
    for (int off = 32; off > 0; off >>= 1) {
        mn = fminf(mn, __shfl_xor(mn, off, 64));
        mx = fmaxf(mx, __shfl_xor(mx, off, 64));
    }
    const float new_min = act_range[0] * 0.999f + mn * 0.001f;
    const float new_max = act_range[1] * 0.999f + mx * 0.001f;
    const float s = (new_max - new_min) / 255.0f;
    const float z = -rintf(new_min / s);         // rintf = round-half-even = jnp.round
    const float inv_s = 1.0f / s;

    const int bc = blockIdx.x * 4 + wave;
    const float gv = g[bc];
    const float4* xp = (const float4*)(x + (size_t)bc * HW);
    floatx4* op = (floatx4*)(out + (size_t)bc * HW);

    #pragma unroll
    for (int k = 0; k < 12; ++k) {
        const int i = lane + k * 64;
        float4 v = xp[i];
        floatx4 r;
        r.x = quant1(v.x * gv, s, z, inv_s);
        r.y = quant1(v.y * gv, s, z, inv_s);
        r.z = quant1(v.z * gv, s, z, inv_s);
        r.w = quant1(v.w * gv, s, z, inv_s);
        __builtin_nontemporal_store(r, op + i);
    }
    if (lane < HW4T) {
        const int i = HW4F + lane;
        float4 v = xp[i];
        floatx4 r;
        r.x = quant1(v.x * gv, s, z, inv_s);
        r.y = quant1(v.y * gv, s, z, inv_s);
        r.z = quant1(v.z * gv, s, z, inv_s);
        r.w = quant1(v.w * gv, s, z, inv_s);
        __builtin_nontemporal_store(r, op + i);
    }
}

extern "C" void kernel_launch(void* const* d_in, const int* in_sizes, int n_in,
                              void* d_out, int out_size, void* d_ws, size_t ws_size,
                              hipStream_t stream) {
    const float* x         = (const float*)d_in[0];
    const float* w1        = (const float*)d_in[1];
    const float* b1        = (const float*)d_in[2];
    const float* w2        = (const float*)d_in[3];
    const float* b2        = (const float*)d_in[4];
    const float* act_range = (const float*)d_in[5];
    float* out = (float*)d_out;

    // ws floats: pooled[16384] | xmn[16384] | xmx[16384] | g[16384] | pmn[64] | pmx[64]
    float* ws     = (float*)d_ws;
    float* pooled = ws;
    float* xmn    = ws + BC;
    float* xmx    = ws + 2 * BC;
    float* g      = ws + 3 * BC;
    float* pmn    = ws + 4 * BC;
    float* pmx    = pmn + B_;

    k_pool <<<BC / 4, 256, 0, stream>>>(x, pooled, xmn, xmx);
    k_mid  <<<B_,     256, 0, stream>>>(pooled, w1, b1, w2, b2, xmn, xmx, g, pmn, pmx);
    k_quant<<<BC / 4, 256, 0, stream>>>(x, g, pmn, pmx, act_range, out);
}